// Round 9
// baseline (396.442 us; speedup 1.0000x reference)
//
#include <hip/hip_runtime.h>
#include <stdint.h>

#define B_ROWS 8192
#define DG 512
#define D2 768
#define D3 1024
#define DCAT 2304
#define DF 256
#define RANK 16
#define AH 512

// bf16 weight buffer element offsets
#define OFF_WG 0
#define OFF_W2 131072
#define OFF_W3 327680
#define OFF_U  589824
#define OFF_V  1638400
#define OFF_S  2686976
#define OFF_WA1 3735552

// workspace byte offsets (R17/R19 layout: zpart overlays a1part, dead after
// post_beta. R18's fence+ticket reduce stays REVERTED.)
#define WS_WBUF  0u            /* 9,830,400 B bf16 weights */
#define WS_GBUF  9830400u      /* 12,582,912 B bf16 LN output (written by fatgemm256) */
#define WS_A1P   22413312u     /* 2 x 8,388,608 B bf16 split-K halves */
#define WS_ZPART 22413312u     /* 4 x 8,388,608 B fp32; overlays a1p (dead after post_beta) */
#define WS_BETA  55967744u     /* 524,288 B */
#define WS_REQUIRED 94240768u

typedef __attribute__((ext_vector_type(8))) short short8;
typedef __attribute__((ext_vector_type(4))) float f32x4;

__device__ inline unsigned short f2bf(float f) {
  union { float f; unsigned int u; } v; v.f = f;
  unsigned int u = v.u + 0x7fffu + ((v.u >> 16) & 1u);
  return (unsigned short)(u >> 16);
}
__device__ inline float bf2f(unsigned short h) {
  union { float f; unsigned int u; } v; v.u = ((unsigned int)h) << 16;
  return v.f;
}

typedef const unsigned int __attribute__((address_space(1)))* as1_u32p;
typedef unsigned int __attribute__((address_space(3)))* as3_u32p;

__device__ inline void g2l16(const unsigned short* g, unsigned short* l) {
  __builtin_amdgcn_global_load_lds((as1_u32p)g, (as3_u32p)l, 16, 0, 0);
}

// ---------------- weight conversion: Wg/W2/W3/Wa1 only (R20) --------------------
// U/V/S conversion moved into fatgemm256's backfill role (bid 224-255) — it is
// needed only by rank_fused, two dispatches later, and hides under the GEMM.

__global__ __launch_bounds__(256) void cvt_w_k(const float* __restrict__ Wg,
                                               const float* __restrict__ W2,
                                               const float* __restrict__ W3,
                                               const float* __restrict__ Wa1,
                                               unsigned short* __restrict__ wbuf) {
  const int e = (blockIdx.x * 256 + threadIdx.x) * 4;   // [0, 1769472)
  const float* src;
  unsigned short* dst;
  if (e < OFF_W2)      { src = Wg + e;             dst = wbuf + e; }
  else if (e < OFF_W3) { src = W2 + (e - OFF_W2);  dst = wbuf + e; }
  else if (e < OFF_U)  { src = W3 + (e - OFF_W3);  dst = wbuf + e; }
  else                 { src = Wa1 + (e - OFF_U);  dst = wbuf + OFF_WA1 + (e - OFF_U); }
  float4 v = *(const float4*)src;
  ushort4 o;
  o.x = f2bf(v.x); o.y = f2bf(v.y); o.z = f2bf(v.z); o.w = f2bf(v.w);
  *(ushort4*)dst = o;
}

// ---------------- fat GEMM: 256x256 tile, BK=64, 8 waves, fp32-A reg-staging ----
// R20: (1) A pipeline deepened to 2 register buffers (arA/arB, loop unrolled x2 —
// all nt even — rule #20: no runtime reg-array index). Ledger: issue order
// A(t),B(t),A(t+1),B(t+1) -> steady vmcnt(12) completes tile t, leaves t+1's 12 in
// flight; A issued ~2 iterations (~2000 cyc) before use, fully covering HBM latency.
// (2) grid 224 -> 256: bid 224-255 backfill-convert U/V/S fp32->bf16 on the 32
// otherwise-idle CUs, concurrent with the GEMM.
// a1 split-K2 18|18 (R19). LN fused in proj epilogue (R16).

__global__ __launch_bounds__(512, 2) void fatgemm256_k(const float* __restrict__ hgf,
                                                       const float* __restrict__ h2f,
                                                       const float* __restrict__ h3f,
                                                       const float* __restrict__ U,
                                                       const float* __restrict__ V,
                                                       const float* __restrict__ S,
                                                       const unsigned short* __restrict__ wbuf,
                                                       unsigned short* __restrict__ wbuf_uvs,
                                                       const float* __restrict__ bg,
                                                       const float* __restrict__ b2,
                                                       const float* __restrict__ b3,
                                                       const float* __restrict__ wg,
                                                       const float* __restrict__ wbg,
                                                       const float* __restrict__ w2,
                                                       const float* __restrict__ wb2,
                                                       const float* __restrict__ w3,
                                                       const float* __restrict__ wb3,
                                                       unsigned short* __restrict__ gout,
                                                       unsigned short* __restrict__ a1part) {
  const int bid = blockIdx.x;
  const int tid = threadIdx.x;

  if (bid >= 224) {
    // ---- backfill role: convert U/V/S (3,145,728 elems) on 32 blocks ----
    const int t0 = (bid - 224) * 512 + tid;         // 0..16383
    for (int i = 0; i < 48; ++i) {
      const size_t e = ((size_t)(t0 + i * 16384)) * 4;  // element offset in [0, 3145728)
      const float* src;
      if (e < 1048576)      src = U + e;
      else if (e < 2097152) src = V + (e - 1048576);
      else                  src = S + (e - 2097152);
      float4 v = *(const float4*)src;
      ushort4 o;
      o.x = f2bf(v.x); o.y = f2bf(v.y); o.z = f2bf(v.z); o.w = f2bf(v.w);
      *(ushort4*)(wbuf_uvs + OFF_U + e) = o;
    }
    return;
  }

  __shared__ __align__(16) unsigned short lA[2 * 256 * 64];  // 64 KB
  __shared__ __align__(16) unsigned short lB[2 * 256 * 64];  // 64 KB
  const int lane = tid & 63;
  const int wid = tid >> 6;          // 0..7
  const int wr = wid >> 2;           // 0..1  (wave tile 128 rows)
  const int wc = wid & 3;            // 0..3  (wave tile 64 cols)
  const int row_s = tid >> 3;        // 0..63 staging row within 64-row phase
  const int kc_s = (((tid & 7) ^ (row_s & 7)) << 3);
  const int mbase = wr * 128 + (lane & 15);
  const int nbase = wc * 64 + (lane & 15);
  const int kq = lane >> 4;
  const int h = lane & 7;

  // block role mapping, longest-first: a1h0(18t) | a1h1(18t) | z2(16t) | z1(12t) | z0(8t)
  int role_a1 = 0, half = 0, m0 = 0, n0 = 0, z = 0, nt = 0;
  if (bid < 128)      { role_a1 = 1; half = bid >> 6; int r6 = bid & 63;
                        n0 = (r6 & 1) << 8; m0 = (r6 >> 1) << 8; nt = 18; }
  else if (bid < 160) { z = 2; m0 = (bid - 128) << 8; nt = 16; }
  else if (bid < 192) { z = 1; m0 = (bid - 160) << 8; nt = 12; }
  else                { z = 0; m0 = (bid - 192) << 8; nt = 8; }

  const float* projA = (z == 0) ? hgf : ((z == 1) ? h2f : h3f);
  const int Kz   = (z == 0) ? DG : ((z == 1) ? D2 : D3);
  const int woff = (z == 0) ? OFF_WG : ((z == 1) ? OFF_W2 : OFF_W3);

  auto loadA = [&](float4 (&ar)[8], int t) {
    const float* Ag; int lda; int ka;
    if (role_a1) {
      const int tt = half * 18 + t;            // global k-tile within DCAT
      if (tt < 8)       { Ag = hgf; lda = DG; ka = tt * 64; }
      else if (tt < 20) { Ag = h2f; lda = D2; ka = (tt - 8) * 64; }
      else              { Ag = h3f; lda = D3; ka = (tt - 20) * 64; }
      Ag += (size_t)m0 * lda;
    } else {
      lda = Kz; Ag = projA + (size_t)m0 * lda; ka = t * 64;
    }
#pragma unroll
    for (int q = 0; q < 4; ++q) {
      const float* src = Ag + (size_t)(q * 64 + row_s) * lda + ka + kc_s;
      ar[q * 2]     = *(const float4*)src;
      ar[q * 2 + 1] = *(const float4*)(src + 4);
    }
  };

  auto writeA = [&](const float4 (&ar)[8], unsigned short* dA) {
#pragma unroll
    for (int q = 0; q < 4; ++q) {
      const float4 a = ar[q * 2], b = ar[q * 2 + 1];
      short8 w;
      w[0] = (short)f2bf(a.x); w[1] = (short)f2bf(a.y);
      w[2] = (short)f2bf(a.z); w[3] = (short)f2bf(a.w);
      w[4] = (short)f2bf(b.x); w[5] = (short)f2bf(b.y);
      w[6] = (short)f2bf(b.z); w[7] = (short)f2bf(b.w);
      *(short8*)(dA + (q * 512 + tid) * 8) = w;   // ds_write_b128, linear -> conflict-free
    }
  };

  auto stageB = [&](int t, unsigned short* dB) {
    const unsigned short* Bg; int ldb; int kb;
    if (role_a1) {
      const int tt = half * 18 + t;
      Bg = wbuf + OFF_WA1 + (size_t)n0 * DCAT; ldb = DCAT; kb = tt * 64;
    } else {
      Bg = wbuf + woff; ldb = Kz; kb = t * 64;
    }
#pragma unroll
    for (int q = 0; q < 4; ++q)
      g2l16(Bg + (size_t)(q * 64 + row_s) * ldb + kb + kc_s, dB + (q * 512 + tid) * 8);
  };

  f32x4 acc[8][4];
#pragma unroll
  for (int ti = 0; ti < 8; ++ti)
#pragma unroll
    for (int tj = 0; tj < 4; ++tj)
      acc[ti][tj] = (f32x4){0.f, 0.f, 0.f, 0.f};

  auto compute = [&](const unsigned short* sA, const unsigned short* sB) {
#pragma unroll
    for (int kk = 0; kk < 2; ++kk) {
      const int kch = (kk << 2) + kq;
      const int ko = ((kch ^ h) << 3);
      short8 af[8], bfr[4];
#pragma unroll
      for (int t4 = 0; t4 < 8; ++t4)
        af[t4] = *(const short8*)(sA + (mbase + t4 * 16) * 64 + ko);
#pragma unroll
      for (int t4 = 0; t4 < 4; ++t4)
        bfr[t4] = *(const short8*)(sB + (nbase + t4 * 16) * 64 + ko);
      __builtin_amdgcn_s_setprio(1);
#pragma unroll
      for (int ti = 0; ti < 8; ++ti)
#pragma unroll
        for (int tj = 0; tj < 4; ++tj)
          acc[ti][tj] = __builtin_amdgcn_mfma_f32_16x16x32_bf16(af[ti], bfr[tj], acc[ti][tj], 0, 0, 0);
      __builtin_amdgcn_s_setprio(0);
    }
  };

  // prologue: A(0), B(0), A(1), B(1) — 24 vmem in flight
  float4 arA[8], arB[8];
  loadA(arA, 0);
  stageB(0, lB);
  loadA(arB, 1);
  stageB(1, lB + 16384);

  for (int t = 0; t < nt; t += 2) {
    // ---- even tile t: regs arA, LDS buf0 ----
    // outstanding: A(t),B(t),A(t+1),B(t+1)=24 -> vmcnt(12) completes tile t's A+B
    asm volatile("s_waitcnt vmcnt(12)" ::: "memory");
    __builtin_amdgcn_sched_barrier(0);
    writeA(arA, lA);
    if (t + 2 < nt) loadA(arA, t + 2);
    asm volatile("s_waitcnt lgkmcnt(0)" ::: "memory");
    __builtin_amdgcn_s_barrier();
    __builtin_amdgcn_sched_barrier(0);
    compute(lA, lB);
    __builtin_amdgcn_sched_barrier(0);
    __builtin_amdgcn_s_barrier();
    if (t + 2 < nt) stageB(t + 2, lB);
    // ---- odd tile t+1: regs arB, LDS buf1 ----
    if (t + 3 < nt) asm volatile("s_waitcnt vmcnt(12)" ::: "memory");
    else            asm volatile("s_waitcnt vmcnt(0)" ::: "memory");
    __builtin_amdgcn_sched_barrier(0);
    writeA(arB, lA + 16384);
    if (t + 3 < nt) loadA(arB, t + 3);
    asm volatile("s_waitcnt lgkmcnt(0)" ::: "memory");
    __builtin_amdgcn_s_barrier();
    __builtin_amdgcn_sched_barrier(0);
    compute(lA + 16384, lB + 16384);
    __builtin_amdgcn_sched_barrier(0);
    __builtin_amdgcn_s_barrier();
    if (t + 3 < nt) stageB(t + 3, lB + 16384);
  }

  if (role_a1) {
    unsigned short* out = a1part + (size_t)half * (B_ROWS * AH);
    const int r0 = m0 + wr * 128 + ((lane >> 4) << 2);
    const int c0 = n0 + wc * 64 + (lane & 15);
#pragma unroll
    for (int ti = 0; ti < 8; ++ti)
#pragma unroll
      for (int tj = 0; tj < 4; ++tj)
#pragma unroll
        for (int i = 0; i < 4; ++i)
          out[(size_t)(r0 + ti * 16 + i) * AH + (c0 + tj * 16)] = f2bf(acc[ti][tj][i]);
  } else {
    // fused bias + LayerNorm + ReLU epilogue (full DF=256 row inside the block)
    const float* bias = (z == 0) ? bg : ((z == 1) ? b2 : b3);
    const float* lnw  = (z == 0) ? wg : ((z == 1) ? w2 : w3);
    const float* lnb  = (z == 0) ? wbg : ((z == 1) ? wb2 : wb3);
    const int cbase = wc * 64 + (lane & 15);
    float bs[4], lw4[4], lb4[4];
#pragma unroll
    for (int tj = 0; tj < 4; ++tj) {
      const int col = cbase + tj * 16;
      bs[tj] = bias[col]; lw4[tj] = lnw[col]; lb4[tj] = lnb[col];
    }
#pragma unroll
    for (int ti = 0; ti < 8; ++ti)
#pragma unroll
      for (int tj = 0; tj < 4; ++tj)
#pragma unroll
        for (int i = 0; i < 4; ++i)
          acc[ti][tj][i] += bs[tj];

    float* lnr = (float*)lA;   // [256 rows][8]: (s,q) per wc; 8 KB
    __syncthreads();           // all tile reads done; safe to reuse lA
#pragma unroll
    for (int ti = 0; ti < 8; ++ti)
#pragma unroll
      for (int i = 0; i < 4; ++i) {
        float s = acc[ti][0][i] + acc[ti][1][i] + acc[ti][2][i] + acc[ti][3][i];
        float q = acc[ti][0][i] * acc[ti][0][i] + acc[ti][1][i] * acc[ti][1][i]
                + acc[ti][2][i] * acc[ti][2][i] + acc[ti][3][i] * acc[ti][3][i];
#pragma unroll
        for (int m = 1; m < 16; m <<= 1) { s += __shfl_xor(s, m, 64); q += __shfl_xor(q, m, 64); }
        if ((lane & 15) == 0) {
          const int rl = wr * 128 + ti * 16 + ((lane >> 4) << 2) + i;
          lnr[rl * 8 + wc * 2]     = s;
          lnr[rl * 8 + wc * 2 + 1] = q;
        }
      }
    __syncthreads();
    unsigned short* gz = gout + (size_t)z * (B_ROWS * DF);
#pragma unroll
    for (int ti = 0; ti < 8; ++ti)
#pragma unroll
      for (int i = 0; i < 4; ++i) {
        const int rl = wr * 128 + ti * 16 + ((lane >> 4) << 2) + i;
        const float4 pa = *(const float4*)(lnr + rl * 8);
        const float4 pb = *(const float4*)(lnr + rl * 8 + 4);
        const float sum = pa.x + pa.z + pb.x + pb.z;
        const float sq  = pa.y + pa.w + pb.y + pb.w;
        const float mean = sum * (1.f / DF);
        const float var  = sq * (1.f / DF) - mean * mean;
        const float rs   = rsqrtf(var + 1e-5f);
        const size_t rowoff = (size_t)(m0 + rl) * DF;
#pragma unroll
        for (int tj = 0; tj < 4; ++tj) {
          const float v = (acc[ti][tj][i] - mean) * rs * lw4[tj] + lb4[tj];
          gz[rowoff + cbase + tj * 16] = f2bf(fmaxf(v, 0.f));
        }
      }
  }
}

// ---------------- fused rank GEMMs: BK=64 dbuf + counted-vmcnt pipeline (R12, frozen) ---
// 75 us, 2 blocks/CU, MfmaUtil 27%, 0 bank conflicts. Plain zpart stores
// (R15 atomics and R18 fence+ticket reduce both regressed badly; zsum_k is cheapest).

__global__ __launch_bounds__(256, 2) void rank_fused_k(const unsigned short* __restrict__ gbuf,
                                                       const unsigned short* __restrict__ wbuf,
                                                       const float* __restrict__ beta,
                                                       float* __restrict__ zpart) {
  __shared__ __align__(16) unsigned short lA[2 * 128 * 64];  // 32 KB
  __shared__ __align__(16) unsigned short lB[2 * 128 * 64];  // 32 KB
  __shared__ float lbeta[4 * 128];                           // 2 KB
  const int m0 = blockIdx.x * 128;
  const int d0 = blockIdx.y * 128;        // output col base within DF
  const int rg = blockIdx.z * 4;          // rank group base
  const int tid = threadIdx.x;

  for (int i = tid; i < 512; i += 256) {
    const int rr = i >> 7, row = i & 127;
    lbeta[i] = beta[(size_t)(m0 + row) * RANK + rg + rr];
  }
  __syncthreads();   // publish lbeta; also drains beta loads so vmcnt counting below is exact

  const int lane = tid & 63;
  const int wr = tid >> 7, wc = (tid >> 6) & 1;
  const int row_s = tid >> 3;        // staging: 8 x 16B chunks per 64-elem row
  const int kc_s = (((tid & 7) ^ ((tid >> 3) & 7)) << 3);
  const int mbase = wr * 64 + (lane & 15);
  const int nbase = wc * 64 + (lane & 15);
  const int kq = lane >> 4;
  const int h = lane & 7;            // row-dependent XOR key
  const int lr0 = wr * 64 + ((lane >> 4) << 2);   // local row base

  // per-thread invariant global bases (row_s + swizzled chunk folded in)
  const unsigned short* Abase = gbuf + (size_t)(m0 + row_s) * DF + kc_s;
  const unsigned short* Bbase = wbuf + OFF_U + (size_t)(rg * 256 + d0 + row_s) * DF + kc_s;

  // stage one BK=64 tile t (t = pass*4 + ks, pass = rr*3+zi) into dA/dB.
  // 8 global_load_lds (vmcnt ops) per thread per call.
  auto stage = [&](int t, unsigned short* dA, unsigned short* dB) {
    const int p = t >> 2, ks = t & 3;
    const int rr = p / 3;
    const int zi = p - rr * 3;
    const unsigned short* Ag = Abase + (size_t)zi * (B_ROWS * DF) + ks * 64;
    const unsigned short* Bg = Bbase + (size_t)zi * 1048576 + (size_t)rr * (256 * DF) + ks * 64;
#pragma unroll
    for (int q = 0; q < 4; ++q) {
      const int lofs = (q * 256 + tid) * 8;
      g2l16(Ag + (size_t)q * 32 * DF, dA + lofs);
      g2l16(Bg + (size_t)q * 32 * DF, dB + lofs);
    }
  };

  f32x4 zacc[4][4], prod[4][4], acc[4][4];
#pragma unroll
  for (int ti = 0; ti < 4; ++ti)
#pragma unroll
    for (int tj = 0; tj < 4; ++tj) {
      zacc[ti][tj] = (f32x4){0.f, 0.f, 0.f, 0.f};
      acc[ti][tj]  = (f32x4){0.f, 0.f, 0.f, 0.f};
    }

  auto compute = [&](const unsigned short* sA, const unsigned short* sB) {
#pragma unroll
    for (int kk = 0; kk < 2; ++kk) {
      const int kch = (kk << 2) + kq;
      const int ko = ((kch ^ h) << 3);
      short8 af[4], bfr[4];
#pragma unroll
      for (int t4 = 0; t4 < 4; ++t4) {
        af[t4]  = *(const short8*)(sA + (mbase + t4 * 16) * 64 + ko);
        bfr[t4] = *(const short8*)(sB + (nbase + t4 * 16) * 64 + ko);
      }
      __builtin_amdgcn_s_setprio(1);
#pragma unroll
      for (int ti = 0; ti < 4; ++ti)
#pragma unroll
        for (int tj = 0; tj < 4; ++tj)
          acc[ti][tj] = __builtin_amdgcn_mfma_f32_16x16x32_bf16(af[ti], bfr[tj], acc[ti][tj], 0, 0, 0);
      __builtin_amdgcn_s_setprio(0);
    }
  };

  // prologue: 2-deep prefetch (16 vmem outstanding per wave)
  stage(0, lA, lB);
  stage(1, lA + 8192, lB + 8192);

  for (int p = 0; p < 12; ++p) {
    const int rr = p / 3;
    const int zi = p - rr * 3;
#pragma unroll
    for (int ks = 0; ks < 4; ++ks) {
      const int t = (p << 2) + ks;
      const int b = t & 1;
      unsigned short* cA = lA + b * 8192;
      unsigned short* cB = lB + b * 8192;
      // wait for tile t's 8 loads; keep t+1's 8 in flight (drain only at last tile)
      if (t < 47) asm volatile("s_waitcnt vmcnt(8)" ::: "memory");
      else        asm volatile("s_waitcnt vmcnt(0)" ::: "memory");
      __builtin_amdgcn_s_barrier();            // all waves' tile-t loads landed
      __builtin_amdgcn_sched_barrier(0);
      compute(cA, cB);
      __builtin_amdgcn_sched_barrier(0);
      __builtin_amdgcn_s_barrier();            // all waves done reading buf b
      if (t + 2 < 48) stage(t + 2, cA, cB);    // overwrite buf b with tile t+2
    }

    if (zi == 0) {
#pragma unroll
      for (int ti = 0; ti < 4; ++ti)
#pragma unroll
        for (int tj = 0; tj < 4; ++tj)
          prod[ti][tj] = acc[ti][tj];
    } else if (zi == 1) {
#pragma unroll
      for (int ti = 0; ti < 4; ++ti)
#pragma unroll
        for (int tj = 0; tj < 4; ++tj)
          prod[ti][tj] *= acc[ti][tj];
    } else {
#pragma unroll
      for (int ti = 0; ti < 4; ++ti) {
        const float4 b4 = *(const float4*)(lbeta + rr * 128 + lr0 + ti * 16);
        const float bv[4] = {b4.x, b4.y, b4.z, b4.w};
#pragma unroll
        for (int tj = 0; tj < 4; ++tj)
#pragma unroll
          for (int i = 0; i < 4; ++i)
            zacc[ti][tj][i] += prod[ti][tj][i] * acc[ti][tj][i] * bv[i];
      }
    }
#pragma unroll
    for (int ti = 0; ti < 4; ++ti)
#pragma unroll
      for (int tj = 0; tj < 4; ++tj)
        acc[ti][tj] = (f32x4){0.f, 0.f, 0.f, 0.f};
  }

  float* zp = zpart + (size_t)blockIdx.z * (B_ROWS * DF);
  const int c0 = d0 + wc * 64 + (lane & 15);
#pragma unroll
  for (int ti = 0; ti < 4; ++ti)
#pragma unroll
    for (int tj = 0; tj < 4; ++tj)
#pragma unroll
      for (int i = 0; i < 4; ++i)
        zp[(size_t)(m0 + lr0 + ti * 16 + i) * DF + (c0 + tj * 16)] = zacc[ti][tj][i];
}

// ---------------- deterministic partial sum: z = zpart0+zpart1+zpart2+zpart3 ----------

__global__ __launch_bounds__(256) void zsum_k(const float* __restrict__ zpart,
                                              float* __restrict__ z) {
  const int idx = blockIdx.x * 256 + threadIdx.x;   // one float4 per thread
  const size_t e = (size_t)idx * 4;
  const size_t stride = (size_t)B_ROWS * DF;
  float4 a = *(const float4*)(zpart + e);
  float4 b = *(const float4*)(zpart + stride + e);
  float4 c = *(const float4*)(zpart + 2 * stride + e);
  float4 d = *(const float4*)(zpart + 3 * stride + e);
  float4 o;
  o.x = (a.x + b.x) + (c.x + d.x);
  o.y = (a.y + b.y) + (c.y + d.y);
  o.z = (a.z + b.z) + (c.z + d.z);
  o.w = (a.w + b.w) + (c.w + d.w);
  *(float4*)(z + e) = o;
}

// ---------------- beta kernel (R12-proven structure, 8 blk/CU TLP) ----------------
// 2048 blocks x 4 rows: bias+relu+logits+softmax -> beta, summing 2 bf16 halves.

__global__ __launch_bounds__(256) void post_beta_k(const unsigned short* __restrict__ a1part,
                                                   const float* __restrict__ ba1,
                                                   const float* __restrict__ Wa2,
                                                   const float* __restrict__ ba2,
                                                   float* __restrict__ beta) {
  __shared__ float lw[RANK * AH];  // 32 KB
  for (int i = threadIdx.x; i < RANK * AH / 4; i += 256)
    *(float4*)(lw + i * 4) = *(const float4*)(Wa2 + i * 4);
  __syncthreads();
  const int row = blockIdx.x * 4 + (threadIdx.x >> 6);
  const int lane = threadIdx.x & 63;
  const unsigned short* h0 = a1part + (size_t)row * AH + lane * 8;
  const unsigned short* h1 = h0 + (size_t)B_ROWS * AH;
  const uint4 p0 = *(const uint4*)h0;
  const uint4 p1 = *(const uint4*)h1;
  const unsigned int u0[4] = {p0.x, p0.y, p0.z, p0.w};
  const unsigned int u1[4] = {p1.x, p1.y, p1.z, p1.w};
  float4 ca = *(const float4*)(ba1 + lane * 8);
  float4 cb = *(const float4*)(ba1 + lane * 8 + 4);
  const float bias[8] = {ca.x, ca.y, ca.z, ca.w, cb.x, cb.y, cb.z, cb.w};
  float av[8];
#pragma unroll
  for (int j = 0; j < 4; ++j) {
    const float s0 = bf2f((unsigned short)(u0[j] & 0xffffu)) + bf2f((unsigned short)(u1[j] & 0xffffu));
    const float s1 = bf2f((unsigned short)(u0[j] >> 16)) + bf2f((unsigned short)(u1[j] >> 16));
    av[2 * j]     = fmaxf(s0 + bias[2 * j], 0.f);
    av[2 * j + 1] = fmaxf(s1 + bias[2 * j + 1], 0.f);
  }
  float lg[RANK];
#pragma unroll
  for (int r = 0; r < RANK; ++r) {
    const float* wrow = lw + r * AH + lane * 8;
    float4 wa = *(const float4*)wrow;
    float4 wb = *(const float4*)(wrow + 4);
    float p = av[0] * wa.x + av[1] * wa.y + av[2] * wa.z + av[3] * wa.w
            + av[4] * wb.x + av[5] * wb.y + av[6] * wb.z + av[7] * wb.w;
#pragma unroll
    for (int m = 1; m < 64; m <<= 1) p += __shfl_xor(p, m, 64);
    lg[r] = p + ba2[r];
  }
  float mx = lg[0];
#pragma unroll
  for (int r = 1; r < RANK; ++r) mx = fmaxf(mx, lg[r]);
  float den = 0.f;
#pragma unroll
  for (int r = 0; r < RANK; ++r) { lg[r] = __expf(lg[r] - mx); den += lg[r]; }
  const float inv = 1.f / den;
  if (lane < RANK) {
    float mine = 0.f;
#pragma unroll
    for (int r = 0; r < RANK; ++r) mine = (lane == r) ? lg[r] : mine;
    beta[(size_t)row * RANK + lane] = mine * inv;
  }
}

// ---------------- launch ----------------

extern "C" void kernel_launch(void* const* d_in, const int* in_sizes, int n_in,
                              void* d_out, int out_size, void* d_ws, size_t ws_size,
                              hipStream_t stream) {
  if (ws_size < (size_t)WS_REQUIRED) return;  // guard: clean fail if ws too small

  const float* h_g   = (const float*)d_in[0];
  const float* h_2d  = (const float*)d_in[1];
  const float* h_3d  = (const float*)d_in[2];
  const float* Wg    = (const float*)d_in[3];
  const float* bg    = (const float*)d_in[4];
  const float* W2    = (const float*)d_in[5];
  const float* b2    = (const float*)d_in[6];
  const float* W3    = (const float*)d_in[7];
  const float* b3    = (const float*)d_in[8];
  const float* ln_g_w = (const float*)d_in[9];
  const float* ln_g_b = (const float*)d_in[10];
  const float* ln_2_w = (const float*)d_in[11];
  const float* ln_2_b = (const float*)d_in[12];
  const float* ln_3_w = (const float*)d_in[13];
  const float* ln_3_b = (const float*)d_in[14];
  const float* U     = (const float*)d_in[15];
  const float* V     = (const float*)d_in[16];
  const float* S     = (const float*)d_in[17];
  const float* Wa1   = (const float*)d_in[18];
  const float* ba1   = (const float*)d_in[19];
  const float* Wa2   = (const float*)d_in[20];
  const float* ba2   = (const float*)d_in[21];

  char* ws = (char*)d_ws;
  unsigned short* wbuf   = (unsigned short*)(ws + WS_WBUF);
  unsigned short* gbuf   = (unsigned short*)(ws + WS_GBUF);
  unsigned short* a1part = (unsigned short*)(ws + WS_A1P);
  float*          zpart  = (float*)(ws + WS_ZPART);   // overlays a1part (dead after post_beta)
  float*          beta   = (float*)(ws + WS_BETA);
  float* z = (float*)d_out;

  cvt_w_k<<<dim3(1728), dim3(256), 0, stream>>>(Wg, W2, W3, Wa1, wbuf);
  fatgemm256_k<<<dim3(256), dim3(512), 0, stream>>>(h_g, h_2d, h_3d, U, V, S, wbuf, wbuf,
                                                    bg, b2, b3,
                                                    ln_g_w, ln_g_b, ln_2_w, ln_2_b,
                                                    ln_3_w, ln_3_b,
                                                    gbuf, a1part);
  post_beta_k<<<dim3(2048), dim3(256), 0, stream>>>(a1part, ba1, Wa2, ba2, beta);
  // a1part dead from here; zpart overlays it.
  rank_fused_k<<<dim3(64, 2, 4), dim3(256), 0, stream>>>(gbuf, wbuf, beta, zpart);
  zsum_k<<<dim3(2048), dim3(256), 0, stream>>>(zpart, z);
}

// Round 10
// 285.184 us; speedup vs baseline: 1.3901x; 1.3901x over previous
//
#include <hip/hip_runtime.h>
#include <stdint.h>

#define B_ROWS 8192
#define DG 512
#define D2 768
#define D3 1024
#define DCAT 2304
#define DF 256
#define RANK 16
#define AH 512

// bf16 weight buffer element offsets
#define OFF_WG 0
#define OFF_W2 131072
#define OFF_W3 327680
#define OFF_U  589824
#define OFF_V  1638400
#define OFF_S  2686976
#define OFF_WA1 3735552

// workspace byte offsets (R17/R19 layout: zpart overlays a1part, dead after
// post_beta. R18's fence+ticket reduce stays REVERTED.)
#define WS_WBUF  0u            /* 9,830,400 B bf16 weights */
#define WS_GBUF  9830400u      /* 12,582,912 B bf16 LN output (written by fatgemm256) */
#define WS_A1P   22413312u     /* 2 x 8,388,608 B bf16 split-K halves */
#define WS_ZPART 22413312u     /* 4 x 8,388,608 B fp32; overlays a1p (dead after post_beta) */
#define WS_BETA  55967744u     /* 524,288 B */
#define WS_REQUIRED 94240768u

typedef __attribute__((ext_vector_type(8))) short short8;
typedef __attribute__((ext_vector_type(4))) float f32x4;

__device__ inline unsigned short f2bf(float f) {
  union { float f; unsigned int u; } v; v.f = f;
  unsigned int u = v.u + 0x7fffu + ((v.u >> 16) & 1u);
  return (unsigned short)(u >> 16);
}
__device__ inline float bf2f(unsigned short h) {
  union { float f; unsigned int u; } v; v.u = ((unsigned int)h) << 16;
  return v.f;
}

typedef const unsigned int __attribute__((address_space(1)))* as1_u32p;
typedef unsigned int __attribute__((address_space(3)))* as3_u32p;

__device__ inline void g2l16(const unsigned short* g, unsigned short* l) {
  __builtin_amdgcn_global_load_lds((as1_u32p)g, (as3_u32p)l, 16, 0, 0);
}

// ---------------- weight conversion: Wg/W2/W3/Wa1 only (R20/R21) ----------------
// U/V/S conversion backfilled in fatgemm256 (bid 224-255) — needed only by
// rank_fused, two dispatches later; hides under the GEMM.

__global__ __launch_bounds__(256) void cvt_w_k(const float* __restrict__ Wg,
                                               const float* __restrict__ W2,
                                               const float* __restrict__ W3,
                                               const float* __restrict__ Wa1,
                                               unsigned short* __restrict__ wbuf) {
  const int e = (blockIdx.x * 256 + threadIdx.x) * 4;   // [0, 1769472)
  const float* src;
  unsigned short* dst;
  if (e < OFF_W2)      { src = Wg + e;             dst = wbuf + e; }
  else if (e < OFF_W3) { src = W2 + (e - OFF_W2);  dst = wbuf + e; }
  else if (e < OFF_U)  { src = W3 + (e - OFF_W3);  dst = wbuf + e; }
  else                 { src = Wa1 + (e - OFF_U);  dst = wbuf + OFF_WA1 + (e - OFF_U); }
  float4 v = *(const float4*)src;
  ushort4 o;
  o.x = f2bf(v.x); o.y = f2bf(v.y); o.z = f2bf(v.z); o.w = f2bf(v.w);
  *(ushort4*)dst = o;
}

// ---------------- fat GEMM: 256x256 tile, BK=64, 8 waves, fp32-A reg-staging ----
// R21: mainloop REVERTED to R19's 1-deep A pipeline. R20's 2-deep A (arA+arB)
// blew the 128-VGPR budget at 512 threads -> scratch spill (FETCH 198 MB /
// WRITE 228 MB, 174 us). Ledger (1-deep): prologue B(0),A(0),B(1); steady
// vmcnt(4) completes B(t)+A(t), leaves B(t+1); drain 0 at last tile only.
// Backfill role kept: bid 224-255 convert U/V/S on the 32 otherwise-idle CUs.
// a1 split-K2 18|18 (R19). LN fused in proj epilogue (R16).

__global__ __launch_bounds__(512, 2) void fatgemm256_k(const float* __restrict__ hgf,
                                                       const float* __restrict__ h2f,
                                                       const float* __restrict__ h3f,
                                                       const float* __restrict__ U,
                                                       const float* __restrict__ V,
                                                       const float* __restrict__ S,
                                                       const unsigned short* __restrict__ wbuf,
                                                       unsigned short* __restrict__ wbuf_uvs,
                                                       const float* __restrict__ bg,
                                                       const float* __restrict__ b2,
                                                       const float* __restrict__ b3,
                                                       const float* __restrict__ wg,
                                                       const float* __restrict__ wbg,
                                                       const float* __restrict__ w2,
                                                       const float* __restrict__ wb2,
                                                       const float* __restrict__ w3,
                                                       const float* __restrict__ wb3,
                                                       unsigned short* __restrict__ gout,
                                                       unsigned short* __restrict__ a1part) {
  const int bid = blockIdx.x;
  const int tid = threadIdx.x;

  if (bid >= 224) {
    // ---- backfill role: convert U/V/S (3,145,728 elems) on 32 blocks ----
    const int t0 = (bid - 224) * 512 + tid;         // 0..16383
    for (int i = 0; i < 48; ++i) {
      const size_t e = ((size_t)(t0 + i * 16384)) * 4;  // element offset in [0, 3145728)
      const float* src;
      if (e < 1048576)      src = U + e;
      else if (e < 2097152) src = V + (e - 1048576);
      else                  src = S + (e - 2097152);
      float4 v = *(const float4*)src;
      ushort4 o;
      o.x = f2bf(v.x); o.y = f2bf(v.y); o.z = f2bf(v.z); o.w = f2bf(v.w);
      *(ushort4*)(wbuf_uvs + OFF_U + e) = o;
    }
    return;
  }

  __shared__ __align__(16) unsigned short lA[2 * 256 * 64];  // 64 KB
  __shared__ __align__(16) unsigned short lB[2 * 256 * 64];  // 64 KB
  const int lane = tid & 63;
  const int wid = tid >> 6;          // 0..7
  const int wr = wid >> 2;           // 0..1  (wave tile 128 rows)
  const int wc = wid & 3;            // 0..3  (wave tile 64 cols)
  const int row_s = tid >> 3;        // 0..63 staging row within 64-row phase
  const int kc_s = (((tid & 7) ^ (row_s & 7)) << 3);
  const int mbase = wr * 128 + (lane & 15);
  const int nbase = wc * 64 + (lane & 15);
  const int kq = lane >> 4;
  const int h = lane & 7;

  // block role mapping, longest-first: a1h0(18t) | a1h1(18t) | z2(16t) | z1(12t) | z0(8t)
  int role_a1 = 0, half = 0, m0 = 0, n0 = 0, z = 0, nt = 0;
  if (bid < 128)      { role_a1 = 1; half = bid >> 6; int r6 = bid & 63;
                        n0 = (r6 & 1) << 8; m0 = (r6 >> 1) << 8; nt = 18; }
  else if (bid < 160) { z = 2; m0 = (bid - 128) << 8; nt = 16; }
  else if (bid < 192) { z = 1; m0 = (bid - 160) << 8; nt = 12; }
  else                { z = 0; m0 = (bid - 192) << 8; nt = 8; }

  const float* projA = (z == 0) ? hgf : ((z == 1) ? h2f : h3f);
  const int Kz   = (z == 0) ? DG : ((z == 1) ? D2 : D3);
  const int woff = (z == 0) ? OFF_WG : ((z == 1) ? OFF_W2 : OFF_W3);

  // A fp32 loads for tile t -> ar[8] (32 VGPRs, single-buffered)
  float4 ar[8];
  auto loadA = [&](int t) {
    const float* Ag; int lda; int ka;
    if (role_a1) {
      const int tt = half * 18 + t;            // global k-tile within DCAT
      if (tt < 8)       { Ag = hgf; lda = DG; ka = tt * 64; }
      else if (tt < 20) { Ag = h2f; lda = D2; ka = (tt - 8) * 64; }
      else              { Ag = h3f; lda = D3; ka = (tt - 20) * 64; }
      Ag += (size_t)m0 * lda;
    } else {
      lda = Kz; Ag = projA + (size_t)m0 * lda; ka = t * 64;
    }
#pragma unroll
    for (int q = 0; q < 4; ++q) {
      const float* src = Ag + (size_t)(q * 64 + row_s) * lda + ka + kc_s;
      ar[q * 2]     = *(const float4*)src;
      ar[q * 2 + 1] = *(const float4*)(src + 4);
    }
  };

  auto writeA = [&](unsigned short* dA) {
#pragma unroll
    for (int q = 0; q < 4; ++q) {
      const float4 a = ar[q * 2], b = ar[q * 2 + 1];
      short8 w;
      w[0] = (short)f2bf(a.x); w[1] = (short)f2bf(a.y);
      w[2] = (short)f2bf(a.z); w[3] = (short)f2bf(a.w);
      w[4] = (short)f2bf(b.x); w[5] = (short)f2bf(b.y);
      w[6] = (short)f2bf(b.z); w[7] = (short)f2bf(b.w);
      *(short8*)(dA + (q * 512 + tid) * 8) = w;   // ds_write_b128, linear -> conflict-free
    }
  };

  auto stageB = [&](int t, unsigned short* dB) {
    const unsigned short* Bg; int ldb; int kb;
    if (role_a1) {
      const int tt = half * 18 + t;
      Bg = wbuf + OFF_WA1 + (size_t)n0 * DCAT; ldb = DCAT; kb = tt * 64;
    } else {
      Bg = wbuf + woff; ldb = Kz; kb = t * 64;
    }
#pragma unroll
    for (int q = 0; q < 4; ++q)
      g2l16(Bg + (size_t)(q * 64 + row_s) * ldb + kb + kc_s, dB + (q * 512 + tid) * 8);
  };

  f32x4 acc[8][4];
#pragma unroll
  for (int ti = 0; ti < 8; ++ti)
#pragma unroll
    for (int tj = 0; tj < 4; ++tj)
      acc[ti][tj] = (f32x4){0.f, 0.f, 0.f, 0.f};

  auto compute = [&](const unsigned short* sA, const unsigned short* sB) {
#pragma unroll
    for (int kk = 0; kk < 2; ++kk) {
      const int kch = (kk << 2) + kq;
      const int ko = ((kch ^ h) << 3);
      short8 af[8], bfr[4];
#pragma unroll
      for (int t4 = 0; t4 < 8; ++t4)
        af[t4] = *(const short8*)(sA + (mbase + t4 * 16) * 64 + ko);
#pragma unroll
      for (int t4 = 0; t4 < 4; ++t4)
        bfr[t4] = *(const short8*)(sB + (nbase + t4 * 16) * 64 + ko);
      __builtin_amdgcn_s_setprio(1);
#pragma unroll
      for (int ti = 0; ti < 8; ++ti)
#pragma unroll
        for (int tj = 0; tj < 4; ++tj)
          acc[ti][tj] = __builtin_amdgcn_mfma_f32_16x16x32_bf16(af[ti], bfr[tj], acc[ti][tj], 0, 0, 0);
      __builtin_amdgcn_s_setprio(0);
    }
  };

  // prologue: B(0), A(0), B(1)  ->  vmcnt(4) at top(0) completes B(0)+A(0), leaves B(1)
  stageB(0, lB);
  loadA(0);
  stageB(1, lB + 16384);

  for (int t = 0; t < nt; ++t) {
    const int b = t & 1;
    unsigned short* cA = lA + b * 16384;
    unsigned short* cB = lB + b * 16384;
    // steady state outstanding: [B(t)(4) leftover, A(t)(8), B(t+1)(4)] -> vmcnt(4)
    if (t + 1 < nt) asm volatile("s_waitcnt vmcnt(4)" ::: "memory");
    else            asm volatile("s_waitcnt vmcnt(0)" ::: "memory");
    __builtin_amdgcn_sched_barrier(0);
    writeA(cA);                       // cvt fp32->bf16 + 4 ds_write_b128
    if (t + 1 < nt) loadA(t + 1);     // A 1-deep: lands under compute(t)
    asm volatile("s_waitcnt lgkmcnt(0)" ::: "memory");
    __builtin_amdgcn_s_barrier();     // all waves' A writes + B(t) landed
    __builtin_amdgcn_sched_barrier(0);
    compute(cA, cB);
    __builtin_amdgcn_sched_barrier(0);
    __builtin_amdgcn_s_barrier();     // all waves done reading buf b
    if (t + 2 < nt) stageB(t + 2, cB);
  }

  if (role_a1) {
    unsigned short* out = a1part + (size_t)half * (B_ROWS * AH);
    const int r0 = m0 + wr * 128 + ((lane >> 4) << 2);
    const int c0 = n0 + wc * 64 + (lane & 15);
#pragma unroll
    for (int ti = 0; ti < 8; ++ti)
#pragma unroll
      for (int tj = 0; tj < 4; ++tj)
#pragma unroll
        for (int i = 0; i < 4; ++i)
          out[(size_t)(r0 + ti * 16 + i) * AH + (c0 + tj * 16)] = f2bf(acc[ti][tj][i]);
  } else {
    // fused bias + LayerNorm + ReLU epilogue (full DF=256 row inside the block)
    const float* bias = (z == 0) ? bg : ((z == 1) ? b2 : b3);
    const float* lnw  = (z == 0) ? wg : ((z == 1) ? w2 : w3);
    const float* lnb  = (z == 0) ? wbg : ((z == 1) ? wb2 : wb3);
    const int cbase = wc * 64 + (lane & 15);
    float bs[4], lw4[4], lb4[4];
#pragma unroll
    for (int tj = 0; tj < 4; ++tj) {
      const int col = cbase + tj * 16;
      bs[tj] = bias[col]; lw4[tj] = lnw[col]; lb4[tj] = lnb[col];
    }
#pragma unroll
    for (int ti = 0; ti < 8; ++ti)
#pragma unroll
      for (int tj = 0; tj < 4; ++tj)
#pragma unroll
        for (int i = 0; i < 4; ++i)
          acc[ti][tj][i] += bs[tj];

    float* lnr = (float*)lA;   // [256 rows][8]: (s,q) per wc; 8 KB
    __syncthreads();           // all tile reads done; safe to reuse lA
#pragma unroll
    for (int ti = 0; ti < 8; ++ti)
#pragma unroll
      for (int i = 0; i < 4; ++i) {
        float s = acc[ti][0][i] + acc[ti][1][i] + acc[ti][2][i] + acc[ti][3][i];
        float q = acc[ti][0][i] * acc[ti][0][i] + acc[ti][1][i] * acc[ti][1][i]
                + acc[ti][2][i] * acc[ti][2][i] + acc[ti][3][i] * acc[ti][3][i];
#pragma unroll
        for (int m = 1; m < 16; m <<= 1) { s += __shfl_xor(s, m, 64); q += __shfl_xor(q, m, 64); }
        if ((lane & 15) == 0) {
          const int rl = wr * 128 + ti * 16 + ((lane >> 4) << 2) + i;
          lnr[rl * 8 + wc * 2]     = s;
          lnr[rl * 8 + wc * 2 + 1] = q;
        }
      }
    __syncthreads();
    unsigned short* gz = gout + (size_t)z * (B_ROWS * DF);
#pragma unroll
    for (int ti = 0; ti < 8; ++ti)
#pragma unroll
      for (int i = 0; i < 4; ++i) {
        const int rl = wr * 128 + ti * 16 + ((lane >> 4) << 2) + i;
        const float4 pa = *(const float4*)(lnr + rl * 8);
        const float4 pb = *(const float4*)(lnr + rl * 8 + 4);
        const float sum = pa.x + pa.z + pb.x + pb.z;
        const float sq  = pa.y + pa.w + pb.y + pb.w;
        const float mean = sum * (1.f / DF);
        const float var  = sq * (1.f / DF) - mean * mean;
        const float rs   = rsqrtf(var + 1e-5f);
        const size_t rowoff = (size_t)(m0 + rl) * DF;
#pragma unroll
        for (int tj = 0; tj < 4; ++tj) {
          const float v = (acc[ti][tj][i] - mean) * rs * lw4[tj] + lb4[tj];
          gz[rowoff + cbase + tj * 16] = f2bf(fmaxf(v, 0.f));
        }
      }
  }
}

// ---------------- fused rank GEMMs: BK=64 dbuf + counted-vmcnt pipeline (R12, frozen) ---
// 75 us, 2 blocks/CU, MfmaUtil 27%, 0 bank conflicts. Plain zpart stores
// (R15 atomics and R18 fence+ticket reduce both regressed badly; zsum_k is cheapest).

__global__ __launch_bounds__(256, 2) void rank_fused_k(const unsigned short* __restrict__ gbuf,
                                                       const unsigned short* __restrict__ wbuf,
                                                       const float* __restrict__ beta,
                                                       float* __restrict__ zpart) {
  __shared__ __align__(16) unsigned short lA[2 * 128 * 64];  // 32 KB
  __shared__ __align__(16) unsigned short lB[2 * 128 * 64];  // 32 KB
  __shared__ float lbeta[4 * 128];                           // 2 KB
  const int m0 = blockIdx.x * 128;
  const int d0 = blockIdx.y * 128;        // output col base within DF
  const int rg = blockIdx.z * 4;          // rank group base
  const int tid = threadIdx.x;

  for (int i = tid; i < 512; i += 256) {
    const int rr = i >> 7, row = i & 127;
    lbeta[i] = beta[(size_t)(m0 + row) * RANK + rg + rr];
  }
  __syncthreads();   // publish lbeta; also drains beta loads so vmcnt counting below is exact

  const int lane = tid & 63;
  const int wr = tid >> 7, wc = (tid >> 6) & 1;
  const int row_s = tid >> 3;        // staging: 8 x 16B chunks per 64-elem row
  const int kc_s = (((tid & 7) ^ ((tid >> 3) & 7)) << 3);
  const int mbase = wr * 64 + (lane & 15);
  const int nbase = wc * 64 + (lane & 15);
  const int kq = lane >> 4;
  const int h = lane & 7;            // row-dependent XOR key
  const int lr0 = wr * 64 + ((lane >> 4) << 2);   // local row base

  // per-thread invariant global bases (row_s + swizzled chunk folded in)
  const unsigned short* Abase = gbuf + (size_t)(m0 + row_s) * DF + kc_s;
  const unsigned short* Bbase = wbuf + OFF_U + (size_t)(rg * 256 + d0 + row_s) * DF + kc_s;

  // stage one BK=64 tile t (t = pass*4 + ks, pass = rr*3+zi) into dA/dB.
  // 8 global_load_lds (vmcnt ops) per thread per call.
  auto stage = [&](int t, unsigned short* dA, unsigned short* dB) {
    const int p = t >> 2, ks = t & 3;
    const int rr = p / 3;
    const int zi = p - rr * 3;
    const unsigned short* Ag = Abase + (size_t)zi * (B_ROWS * DF) + ks * 64;
    const unsigned short* Bg = Bbase + (size_t)zi * 1048576 + (size_t)rr * (256 * DF) + ks * 64;
#pragma unroll
    for (int q = 0; q < 4; ++q) {
      const int lofs = (q * 256 + tid) * 8;
      g2l16(Ag + (size_t)q * 32 * DF, dA + lofs);
      g2l16(Bg + (size_t)q * 32 * DF, dB + lofs);
    }
  };

  f32x4 zacc[4][4], prod[4][4], acc[4][4];
#pragma unroll
  for (int ti = 0; ti < 4; ++ti)
#pragma unroll
    for (int tj = 0; tj < 4; ++tj) {
      zacc[ti][tj] = (f32x4){0.f, 0.f, 0.f, 0.f};
      acc[ti][tj]  = (f32x4){0.f, 0.f, 0.f, 0.f};
    }

  auto compute = [&](const unsigned short* sA, const unsigned short* sB) {
#pragma unroll
    for (int kk = 0; kk < 2; ++kk) {
      const int kch = (kk << 2) + kq;
      const int ko = ((kch ^ h) << 3);
      short8 af[4], bfr[4];
#pragma unroll
      for (int t4 = 0; t4 < 4; ++t4) {
        af[t4]  = *(const short8*)(sA + (mbase + t4 * 16) * 64 + ko);
        bfr[t4] = *(const short8*)(sB + (nbase + t4 * 16) * 64 + ko);
      }
      __builtin_amdgcn_s_setprio(1);
#pragma unroll
      for (int ti = 0; ti < 4; ++ti)
#pragma unroll
        for (int tj = 0; tj < 4; ++tj)
          acc[ti][tj] = __builtin_amdgcn_mfma_f32_16x16x32_bf16(af[ti], bfr[tj], acc[ti][tj], 0, 0, 0);
      __builtin_amdgcn_s_setprio(0);
    }
  };

  // prologue: 2-deep prefetch (16 vmem outstanding per wave)
  stage(0, lA, lB);
  stage(1, lA + 8192, lB + 8192);

  for (int p = 0; p < 12; ++p) {
    const int rr = p / 3;
    const int zi = p - rr * 3;
#pragma unroll
    for (int ks = 0; ks < 4; ++ks) {
      const int t = (p << 2) + ks;
      const int b = t & 1;
      unsigned short* cA = lA + b * 8192;
      unsigned short* cB = lB + b * 8192;
      // wait for tile t's 8 loads; keep t+1's 8 in flight (drain only at last tile)
      if (t < 47) asm volatile("s_waitcnt vmcnt(8)" ::: "memory");
      else        asm volatile("s_waitcnt vmcnt(0)" ::: "memory");
      __builtin_amdgcn_s_barrier();            // all waves' tile-t loads landed
      __builtin_amdgcn_sched_barrier(0);
      compute(cA, cB);
      __builtin_amdgcn_sched_barrier(0);
      __builtin_amdgcn_s_barrier();            // all waves done reading buf b
      if (t + 2 < 48) stage(t + 2, cA, cB);    // overwrite buf b with tile t+2
    }

    if (zi == 0) {
#pragma unroll
      for (int ti = 0; ti < 4; ++ti)
#pragma unroll
        for (int tj = 0; tj < 4; ++tj)
          prod[ti][tj] = acc[ti][tj];
    } else if (zi == 1) {
#pragma unroll
      for (int ti = 0; ti < 4; ++ti)
#pragma unroll
        for (int tj = 0; tj < 4; ++tj)
          prod[ti][tj] *= acc[ti][tj];
    } else {
#pragma unroll
      for (int ti = 0; ti < 4; ++ti) {
        const float4 b4 = *(const float4*)(lbeta + rr * 128 + lr0 + ti * 16);
        const float bv[4] = {b4.x, b4.y, b4.z, b4.w};
#pragma unroll
        for (int tj = 0; tj < 4; ++tj)
#pragma unroll
          for (int i = 0; i < 4; ++i)
            zacc[ti][tj][i] += prod[ti][tj][i] * acc[ti][tj][i] * bv[i];
      }
    }
#pragma unroll
    for (int ti = 0; ti < 4; ++ti)
#pragma unroll
      for (int tj = 0; tj < 4; ++tj)
        acc[ti][tj] = (f32x4){0.f, 0.f, 0.f, 0.f};
  }

  float* zp = zpart + (size_t)blockIdx.z * (B_ROWS * DF);
  const int c0 = d0 + wc * 64 + (lane & 15);
#pragma unroll
  for (int ti = 0; ti < 4; ++ti)
#pragma unroll
    for (int tj = 0; tj < 4; ++tj)
#pragma unroll
      for (int i = 0; i < 4; ++i)
        zp[(size_t)(m0 + lr0 + ti * 16 + i) * DF + (c0 + tj * 16)] = zacc[ti][tj][i];
}

// ---------------- deterministic partial sum: z = zpart0+zpart1+zpart2+zpart3 ----------

__global__ __launch_bounds__(256) void zsum_k(const float* __restrict__ zpart,
                                              float* __restrict__ z) {
  const int idx = blockIdx.x * 256 + threadIdx.x;   // one float4 per thread
  const size_t e = (size_t)idx * 4;
  const size_t stride = (size_t)B_ROWS * DF;
  float4 a = *(const float4*)(zpart + e);
  float4 b = *(const float4*)(zpart + stride + e);
  float4 c = *(const float4*)(zpart + 2 * stride + e);
  float4 d = *(const float4*)(zpart + 3 * stride + e);
  float4 o;
  o.x = (a.x + b.x) + (c.x + d.x);
  o.y = (a.y + b.y) + (c.y + d.y);
  o.z = (a.z + b.z) + (c.z + d.z);
  o.w = (a.w + b.w) + (c.w + d.w);
  *(float4*)(z + e) = o;
}

// ---------------- beta kernel (R12-proven structure, 8 blk/CU TLP) ----------------
// 2048 blocks x 4 rows: bias+relu+logits+softmax -> beta, summing 2 bf16 halves.

__global__ __launch_bounds__(256) void post_beta_k(const unsigned short* __restrict__ a1part,
                                                   const float* __restrict__ ba1,
                                                   const float* __restrict__ Wa2,
                                                   const float* __restrict__ ba2,
                                                   float* __restrict__ beta) {
  __shared__ float lw[RANK * AH];  // 32 KB
  for (int i = threadIdx.x; i < RANK * AH / 4; i += 256)
    *(float4*)(lw + i * 4) = *(const float4*)(Wa2 + i * 4);
  __syncthreads();
  const int row = blockIdx.x * 4 + (threadIdx.x >> 6);
  const int lane = threadIdx.x & 63;
  const unsigned short* h0 = a1part + (size_t)row * AH + lane * 8;
  const unsigned short* h1 = h0 + (size_t)B_ROWS * AH;
  const uint4 p0 = *(const uint4*)h0;
  const uint4 p1 = *(const uint4*)h1;
  const unsigned int u0[4] = {p0.x, p0.y, p0.z, p0.w};
  const unsigned int u1[4] = {p1.x, p1.y, p1.z, p1.w};
  float4 ca = *(const float4*)(ba1 + lane * 8);
  float4 cb = *(const float4*)(ba1 + lane * 8 + 4);
  const float bias[8] = {ca.x, ca.y, ca.z, ca.w, cb.x, cb.y, cb.z, cb.w};
  float av[8];
#pragma unroll
  for (int j = 0; j < 4; ++j) {
    const float s0 = bf2f((unsigned short)(u0[j] & 0xffffu)) + bf2f((unsigned short)(u1[j] & 0xffffu));
    const float s1 = bf2f((unsigned short)(u0[j] >> 16)) + bf2f((unsigned short)(u1[j] >> 16));
    av[2 * j]     = fmaxf(s0 + bias[2 * j], 0.f);
    av[2 * j + 1] = fmaxf(s1 + bias[2 * j + 1], 0.f);
  }
  float lg[RANK];
#pragma unroll
  for (int r = 0; r < RANK; ++r) {
    const float* wrow = lw + r * AH + lane * 8;
    float4 wa = *(const float4*)wrow;
    float4 wb = *(const float4*)(wrow + 4);
    float p = av[0] * wa.x + av[1] * wa.y + av[2] * wa.z + av[3] * wa.w
            + av[4] * wb.x + av[5] * wb.y + av[6] * wb.z + av[7] * wb.w;
#pragma unroll
    for (int m = 1; m < 64; m <<= 1) p += __shfl_xor(p, m, 64);
    lg[r] = p + ba2[r];
  }
  float mx = lg[0];
#pragma unroll
  for (int r = 1; r < RANK; ++r) mx = fmaxf(mx, lg[r]);
  float den = 0.f;
#pragma unroll
  for (int r = 0; r < RANK; ++r) { lg[r] = __expf(lg[r] - mx); den += lg[r]; }
  const float inv = 1.f / den;
  if (lane < RANK) {
    float mine = 0.f;
#pragma unroll
    for (int r = 0; r < RANK; ++r) mine = (lane == r) ? lg[r] : mine;
    beta[(size_t)row * RANK + lane] = mine * inv;
  }
}

// ---------------- launch ----------------

extern "C" void kernel_launch(void* const* d_in, const int* in_sizes, int n_in,
                              void* d_out, int out_size, void* d_ws, size_t ws_size,
                              hipStream_t stream) {
  if (ws_size < (size_t)WS_REQUIRED) return;  // guard: clean fail if ws too small

  const float* h_g   = (const float*)d_in[0];
  const float* h_2d  = (const float*)d_in[1];
  const float* h_3d  = (const float*)d_in[2];
  const float* Wg    = (const float*)d_in[3];
  const float* bg    = (const float*)d_in[4];
  const float* W2    = (const float*)d_in[5];
  const float* b2    = (const float*)d_in[6];
  const float* W3    = (const float*)d_in[7];
  const float* b3    = (const float*)d_in[8];
  const float* ln_g_w = (const float*)d_in[9];
  const float* ln_g_b = (const float*)d_in[10];
  const float* ln_2_w = (const float*)d_in[11];
  const float* ln_2_b = (const float*)d_in[12];
  const float* ln_3_w = (const float*)d_in[13];
  const float* ln_3_b = (const float*)d_in[14];
  const float* U     = (const float*)d_in[15];
  const float* V     = (const float*)d_in[16];
  const float* S     = (const float*)d_in[17];
  const float* Wa1   = (const float*)d_in[18];
  const float* ba1   = (const float*)d_in[19];
  const float* Wa2   = (const float*)d_in[20];
  const float* ba2   = (const float*)d_in[21];

  char* ws = (char*)d_ws;
  unsigned short* wbuf   = (unsigned short*)(ws + WS_WBUF);
  unsigned short* gbuf   = (unsigned short*)(ws + WS_GBUF);
  unsigned short* a1part = (unsigned short*)(ws + WS_A1P);
  float*          zpart  = (float*)(ws + WS_ZPART);   // overlays a1part (dead after post_beta)
  float*          beta   = (float*)(ws + WS_BETA);
  float* z = (float*)d_out;

  cvt_w_k<<<dim3(1728), dim3(256), 0, stream>>>(Wg, W2, W3, Wa1, wbuf);
  fatgemm256_k<<<dim3(256), dim3(512), 0, stream>>>(h_g, h_2d, h_3d, U, V, S, wbuf, wbuf,
                                                    bg, b2, b3,
                                                    ln_g_w, ln_g_b, ln_2_w, ln_2_b,
                                                    ln_3_w, ln_3_b,
                                                    gbuf, a1part);
  post_beta_k<<<dim3(2048), dim3(256), 0, stream>>>(a1part, ba1, Wa2, ba2, beta);
  // a1part dead from here; zpart overlays it.
  rank_fused_k<<<dim3(64, 2, 4), dim3(256), 0, stream>>>(gbuf, wbuf, beta, zpart);
  zsum_k<<<dim3(2048), dim3(256), 0, stream>>>(zpart, z);
}